// Round 4
// baseline (829.251 us; speedup 1.0000x reference)
//
#include <hip/hip_runtime.h>
#include <hip/hip_bf16.h>
#include <stdint.h>

#define S_LEN 2048
#define NROW  4096            // B*S
#define DQKV  3072            // 2048 Q + 512 K + 512 V

typedef unsigned short u16;
typedef __attribute__((ext_vector_type(8))) short bf16x8;
typedef __attribute__((ext_vector_type(4))) float f32x4;

__device__ __forceinline__ float bf2f(u16 v) {
  unsigned int u = ((unsigned int)v) << 16;
  return __builtin_bit_cast(float, u);
}
__device__ __forceinline__ u16 f2bf(float f) {
  unsigned int u = __builtin_bit_cast(unsigned int, f);
  u += 0x7FFFu + ((u >> 16) & 1u);
  return (u16)(u >> 16);
}
__device__ __forceinline__ void async16(const void* g, void* l) {
  __builtin_amdgcn_global_load_lds(
      (const __attribute__((address_space(1))) unsigned int*)(uintptr_t)g,
      (__attribute__((address_space(3))) unsigned int*)(uintptr_t)l, 16, 0, 0);
}
#define LGKM0  do { asm volatile("s_waitcnt lgkmcnt(0)" ::: "memory"); \
                    __builtin_amdgcn_sched_barrier(0); } while (0)
#define VMC(n) do { asm volatile("s_waitcnt vmcnt(" #n ")" ::: "memory"); \
                    __builtin_amdgcn_sched_barrier(0); } while (0)
#define BAR()  __builtin_amdgcn_s_barrier()

// ---------------- transpose f32 [R][C] -> bf16 [C][R] ----------------
__global__ __launch_bounds__(256) void transpose_f32_bf16(
    const float* __restrict__ in, u16* __restrict__ out, int R, int C) {
  __shared__ float t[32][33];
  const int bx = blockIdx.x * 32;
  const int by = blockIdx.y * 32;
  const int tx = threadIdx.x, ty = threadIdx.y;   // 32 x 8
#pragma unroll
  for (int i = 0; i < 32; i += 8)
    t[ty + i][tx] = in[(size_t)(by + ty + i) * C + bx + tx];
  __syncthreads();
#pragma unroll
  for (int i = 0; i < 32; i += 8)
    out[(size_t)(bx + ty + i) * R + by + tx] = f2bf(t[tx][ty + i]);
}

// ---------------- RoPE tables ----------------
__global__ __launch_bounds__(256) void rope_tables(float* __restrict__ cosT,
                                                   float* __restrict__ sinT) {
  int idx = blockIdx.x * 256 + threadIdx.x;   // 2048*64
  int i = idx & 63, s = idx >> 6;
  float inv = powf(10000.0f, -2.0f * (float)i / 128.0f);
  float ang = (float)s * inv;
  cosT[idx] = cosf(ang);
  sinT[idx] = sinf(ang);
}

// ---------------- RoPE in-place on QKV ----------------
__global__ __launch_bounds__(256) void rope_apply(u16* __restrict__ QKV,
                                                  const float* __restrict__ cosT,
                                                  const float* __restrict__ sinT) {
  int idx = blockIdx.x * 256 + threadIdx.x;        // NROW*20*64
  int i = idx & 63;
  int h20 = (idx >> 6) % 20;
  int row = idx / (64 * 20);
  int s = row & (S_LEN - 1);
  int col = (h20 < 16) ? (h20 * 128) : (2048 + (h20 - 16) * 128);
  size_t base = (size_t)row * DQKV + col;
  float v1 = bf2f(QKV[base + i]);
  float v2 = bf2f(QKV[base + 64 + i]);
  float c = cosT[s * 64 + i], sn = sinT[s * 64 + i];
  QKV[base + i]      = f2bf(v1 * c - v2 * sn);
  QKV[base + 64 + i] = f2bf(v1 * sn + v2 * c);
}

// ---------------- RMSNorm: f32 [rows][2048] -> bf16 ----------------
__global__ __launch_bounds__(256) void rmsnorm_kernel(const float* __restrict__ x,
                                                      const float* __restrict__ g,
                                                      u16* __restrict__ out) {
  const int row = blockIdx.x, tid = threadIdx.x;
  const float* xr = x + (size_t)row * 2048;
  float4 a = ((const float4*)xr)[tid * 2];
  float4 b = ((const float4*)xr)[tid * 2 + 1];
  float ss = a.x*a.x + a.y*a.y + a.z*a.z + a.w*a.w
           + b.x*b.x + b.y*b.y + b.z*b.z + b.w*b.w;
#pragma unroll
  for (int m = 1; m < 64; m <<= 1) ss += __shfl_xor(ss, m, 64);
  __shared__ float red[4];
  if ((tid & 63) == 0) red[tid >> 6] = ss;
  __syncthreads();
  float tot = red[0] + red[1] + red[2] + red[3];
  float rms = rsqrtf(tot * (1.0f / 2048.0f) + 1e-5f);
  const int c = tid * 8;
  float v[8] = {a.x,a.y,a.z,a.w,b.x,b.y,b.z,b.w};
  u16 o[8];
#pragma unroll
  for (int j = 0; j < 8; j++) o[j] = f2bf(v[j] * rms * g[c + j]);
  *(uint4*)(out + (size_t)row * 2048 + c) = *(uint4*)o;
}

// ======================= 4-phase double-buffered GEMM =======================
// C[M][N] = A[M][K] * Bt[N][K], BM=256, BK=64, 8 waves (2m x 4n), 512 thr.
// LDS tile: rows of 128B (BK=64 bf16), chunk swizzle: slot = chunk ^ (row&7).
// Quarter schedule: B-h0(t+1)@p0, B-h1(t+1)@p1, A-q0(t+2)@p2, A-q1(t+2)@p3.
// Single counted vmcnt(2) per K-tile (phase 3).  MODE 0: bf16 out.
// MODE 1: f32 out = acc + bias? + res.
template <int BN, int MODE>
__global__ __launch_bounds__(512, 2) void gemm8p(
    const u16* __restrict__ A, const u16* __restrict__ Bt,
    int nx, int K, int N,
    const float* __restrict__ bias, const float* __restrict__ res,
    u16* __restrict__ outb, float* __restrict__ outf) {
  constexpr int NF = BN / 64;            // frags per wave in n (4 or 2)
  constexpr int BB = BN * 128;           // bytes per B buffer
  __shared__ char ldsA[2 * 32768] __attribute__((aligned(16)));
  __shared__ char ldsB[2 * BB]    __attribute__((aligned(16)));
  const int t = threadIdx.x;
  const int nwg = gridDim.x;
  const int wg = ((int)blockIdx.x & 7) * (nwg >> 3) + ((int)blockIdx.x >> 3);
  const int m0 = (wg / nx) * 256, n0 = (wg % nx) * BN;
  const int l = t & 63, w = t >> 6;
  const int wm = w >> 2, wn = w & 3;
  const int lr = l & 15, lg = l >> 4;

  const size_t K2 = (size_t)K * 2;
  const int pr = t >> 3;                          // 0..63
  const int ckb = ((t & 7) ^ (pr & 7)) * 16;      // swizzled source chunk
  const int t16 = t * 16;
  const char* aSrc = (const char*)A  + (size_t)(m0 + pr) * K2 + ckb;
  const char* bSrc = (const char*)Bt + (size_t)(n0 + pr) * K2 + ckb;

  auto ST_A = [&](int q, int kt, int buf) {
    char* d = ldsA + buf * 32768 + q * 16384 + t16;
    const char* s = aSrc + (size_t)(q * 128) * K2 + (size_t)kt * 128;
    async16(s, d);
    async16(s + (size_t)64 * K2, d + 8192);
  };
  auto ST_B = [&](int h, int kt, int buf) {
    if constexpr (BN == 256) {
      char* d = ldsB + buf * 32768 + h * 16384 + t16;
      const char* s = bSrc + (size_t)(h * 128) * K2 + (size_t)kt * 128;
      async16(s, d);
      async16(s + (size_t)64 * K2, d + 8192);
    } else {
      char* d = ldsB + buf * 16384 + h * 8192 + t16;
      const char* s = bSrc + (size_t)(h * 64) * K2 + (size_t)kt * 128;
      async16(s, d);
    }
  };

  const int NT = K >> 6;
  // prologue: tile0 (A0,A1,B0,B1) + tile1 (A0,A1)
  ST_A(0, 0, 0); ST_A(1, 0, 0); ST_B(0, 0, 0); ST_B(1, 0, 0);
  ST_A(0, 1, 1); ST_A(1, 1, 1);
  VMC(4);
  BAR();

  // read addressing
  const int key = lr & 7;
  const int c0 = (lg ^ key) * 16;
  const int c1 = ((4 + lg) ^ key) * 16;
  const int aB = wm * 16384 + lr * 128;
  const int bB = (BN == 256) ? ((wn >> 1) * 16384 + ((wn & 1) * 64 + lr) * 128)
                             : ((wn >> 1) * 8192  + ((wn & 1) * 32 + lr) * 128);

  f32x4 acc[8][NF] = {};

  for (int kt = 0; kt < NT; ++kt) {
    const int bufc = kt & 1, bufn = bufc ^ 1;
    const int t1 = (kt + 1 < NT) ? kt + 1 : 0;
    const int t2 = (kt + 2 < NT) ? kt + 2 : kt + 2 - NT;
    const char* sA = ldsA + bufc * 32768;
    const char* sB = ldsB + bufc * BB;
    bf16x8 aF0[8], aF1[8], bF0[NF], bF1[NF];
    // ---- phase 0: read A-kh0, B-kh0; stage B-h0(t+1); mfma kh0 m0-3
#pragma unroll
    for (int m = 0; m < 8; m++) aF0[m] = *(const bf16x8*)(sA + aB + m * 2048 + c0);
#pragma unroll
    for (int n = 0; n < NF; n++) bF0[n] = *(const bf16x8*)(sB + bB + n * 2048 + c0);
    LGKM0;
    BAR();
    ST_B(0, t1, bufn);
    __builtin_amdgcn_s_setprio(1);
#pragma unroll
    for (int m = 0; m < 4; m++)
#pragma unroll
      for (int n = 0; n < NF; n++)
        acc[m][n] = __builtin_amdgcn_mfma_f32_16x16x32_bf16(aF0[m], bF0[n], acc[m][n], 0, 0, 0);
    __builtin_amdgcn_s_setprio(0);
    BAR();
    // ---- phase 1: read A-kh1; stage B-h1(t+1); mfma kh0 m4-7
#pragma unroll
    for (int m = 0; m < 8; m++) aF1[m] = *(const bf16x8*)(sA + aB + m * 2048 + c1);
    LGKM0;
    BAR();
    ST_B(1, t1, bufn);
    __builtin_amdgcn_s_setprio(1);
#pragma unroll
    for (int m = 4; m < 8; m++)
#pragma unroll
      for (int n = 0; n < NF; n++)
        acc[m][n] = __builtin_amdgcn_mfma_f32_16x16x32_bf16(aF0[m], bF0[n], acc[m][n], 0, 0, 0);
    __builtin_amdgcn_s_setprio(0);
    BAR();
    // ---- phase 2: read B-kh1; stage A-q0(t+2); mfma kh1 m0-3
#pragma unroll
    for (int n = 0; n < NF; n++) bF1[n] = *(const bf16x8*)(sB + bB + n * 2048 + c1);
    LGKM0;
    BAR();
    ST_A(0, t2, bufc);
    __builtin_amdgcn_s_setprio(1);
#pragma unroll
    for (int m = 0; m < 4; m++)
#pragma unroll
      for (int n = 0; n < NF; n++)
        acc[m][n] = __builtin_amdgcn_mfma_f32_16x16x32_bf16(aF1[m], bF1[n], acc[m][n], 0, 0, 0);
    __builtin_amdgcn_s_setprio(0);
    BAR();
    // ---- phase 3: vmcnt(2); stage A-q1(t+2); mfma kh1 m4-7
    VMC(2);
    BAR();
    ST_A(1, t2, bufc);
    __builtin_amdgcn_s_setprio(1);
#pragma unroll
    for (int m = 4; m < 8; m++)
#pragma unroll
      for (int n = 0; n < NF; n++)
        acc[m][n] = __builtin_amdgcn_mfma_f32_16x16x32_bf16(aF1[m], bF1[n], acc[m][n], 0, 0, 0);
    __builtin_amdgcn_s_setprio(0);
    BAR();
  }

#pragma unroll
  for (int m = 0; m < 8; m++) {
    const int row = m0 + wm * 128 + m * 16 + lg * 4;
#pragma unroll
    for (int n = 0; n < NF; n++) {
      const int col = n0 + wn * (BN / 4) + n * 16 + lr;
      const float bv = bias ? bias[col] : 0.0f;
#pragma unroll
      for (int r = 0; r < 4; r++) {
        const size_t idx = (size_t)(row + r) * N + col;
        float v = acc[m][n][r] + bv;
        if (MODE == 0) outb[idx] = f2bf(v);
        else           outf[idx] = v + res[idx];
      }
    }
  }
}

// ============ fused SwiGLU, same 4-phase schedule ============
// B buffer = g-panel(16K) || u-panel(16K). out = silu(g+bg)*(u+bu), bf16.
__global__ __launch_bounds__(512, 2) void swiglu8p(
    const u16* __restrict__ A, const u16* __restrict__ Bg, const u16* __restrict__ Bu,
    int nx, int K, const float* __restrict__ bgv, const float* __restrict__ buv,
    u16* __restrict__ out) {
  __shared__ char ldsA[2 * 32768] __attribute__((aligned(16)));
  __shared__ char ldsB[2 * 32768] __attribute__((aligned(16)));
  const int t = threadIdx.x;
  const int nwg = gridDim.x;
  const int wg = ((int)blockIdx.x & 7) * (nwg >> 3) + ((int)blockIdx.x >> 3);
  const int m0 = (wg / nx) * 256, n0 = (wg % nx) * 128;
  const int l = t & 63, w = t >> 6;
  const int wm = w >> 2, wn = w & 3;
  const int lr = l & 15, lg = l >> 4;

  const size_t K2 = (size_t)K * 2;
  const int pr = t >> 3;
  const int ckb = ((t & 7) ^ (pr & 7)) * 16;
  const int t16 = t * 16;
  const char* aSrc = (const char*)A  + (size_t)(m0 + pr) * K2 + ckb;
  const char* gSrc = (const char*)Bg + (size_t)(n0 + pr) * K2 + ckb;
  const char* uSrc = (const char*)Bu + (size_t)(n0 + pr) * K2 + ckb;

  auto ST_A = [&](int q, int kt, int buf) {
    char* d = ldsA + buf * 32768 + q * 16384 + t16;
    const char* s = aSrc + (size_t)(q * 128) * K2 + (size_t)kt * 128;
    async16(s, d);
    async16(s + (size_t)64 * K2, d + 8192);
  };
  auto ST_GU = [&](int h, int kt, int buf) {   // h=0: g, h=1: u
    char* d = ldsB + buf * 32768 + h * 16384 + t16;
    const char* s = (h ? uSrc : gSrc) + (size_t)kt * 128;
    async16(s, d);
    async16(s + (size_t)64 * K2, d + 8192);
  };

  const int NT = K >> 6;
  ST_A(0, 0, 0); ST_A(1, 0, 0); ST_GU(0, 0, 0); ST_GU(1, 0, 0);
  ST_A(0, 1, 1); ST_A(1, 1, 1);
  VMC(4);
  BAR();

  const int key = lr & 7;
  const int c0 = (lg ^ key) * 16;
  const int c1 = ((4 + lg) ^ key) * 16;
  const int aB = wm * 16384 + lr * 128;
  const int gB = (wn * 32 + lr) * 128;

  f32x4 accg[8][2] = {}, accu[8][2] = {};

  for (int kt = 0; kt < NT; ++kt) {
    const int bufc = kt & 1, bufn = bufc ^ 1;
    const int t1 = (kt + 1 < NT) ? kt + 1 : 0;
    const int t2 = (kt + 2 < NT) ? kt + 2 : kt + 2 - NT;
    const char* sA = ldsA + bufc * 32768;
    const char* sB = ldsB + bufc * 32768;
    bf16x8 aF0[8], aF1[8], gF0[2], gF1[2], uF0[2], uF1[2];
    // ---- phase 0: read A-kh0, g/u-kh0; stage G(t+1); mfma g-kh0 (all m)
#pragma unroll
    for (int m = 0; m < 8; m++) aF0[m] = *(const bf16x8*)(sA + aB + m * 2048 + c0);
#pragma unroll
    for (int n = 0; n < 2; n++) {
      gF0[n] = *(const bf16x8*)(sB + gB + n * 2048 + c0);
      uF0[n] = *(const bf16x8*)(sB + 16384 + gB + n * 2048 + c0);
    }
    LGKM0;
    BAR();
    ST_GU(0, t1, bufn);
    __builtin_amdgcn_s_setprio(1);
#pragma unroll
    for (int m = 0; m < 8; m++)
#pragma unroll
      for (int n = 0; n < 2; n++)
        accg[m][n] = __builtin_amdgcn_mfma_f32_16x16x32_bf16(aF0[m], gF0[n], accg[m][n], 0, 0, 0);
    __builtin_amdgcn_s_setprio(0);
    BAR();
    // ---- phase 1: read A-kh1; stage U(t+1); mfma u-kh0
#pragma unroll
    for (int m = 0; m < 8; m++) aF1[m] = *(const bf16x8*)(sA + aB + m * 2048 + c1);
    LGKM0;
    BAR();
    ST_GU(1, t1, bufn);
    __builtin_amdgcn_s_setprio(1);
#pragma unroll
    for (int m = 0; m < 8; m++)
#pragma unroll
      for (int n = 0; n < 2; n++)
        accu[m][n] = __builtin_amdgcn_mfma_f32_16x16x32_bf16(aF0[m], uF0[n], accu[m][n], 0, 0, 0);
    __builtin_amdgcn_s_setprio(0);
    BAR();
    // ---- phase 2: read g/u-kh1; stage A-q0(t+2); mfma g-kh1
#pragma unroll
    for (int n = 0; n < 2; n++) {
      gF1[n] = *(const bf16x8*)(sB + gB + n * 2048 + c1);
      uF1[n] = *(const bf16x8*)(sB + 16384 + gB + n * 2048 + c1);
    }
    LGKM0;
    BAR();
    ST_A(0, t2, bufc);
    __builtin_amdgcn_s_setprio(1);
#pragma unroll
    for (int m = 0; m < 8; m++)
#pragma unroll
      for (int n = 0; n < 2; n++)
        accg[m][n] = __builtin_amdgcn_mfma_f32_16x16x32_bf16(aF1[m], gF1[n], accg[m][n], 0, 0, 0);
    __builtin_amdgcn_s_setprio(0);
    BAR();
    // ---- phase 3: vmcnt(2); stage A-q1(t+2); mfma u-kh1
    VMC(2);
    BAR();
    ST_A(1, t2, bufc);
    __builtin_amdgcn_s_setprio(1);
#pragma unroll
    for (int m = 0; m < 8; m++)
#pragma unroll
      for (int n = 0; n < 2; n++)
        accu[m][n] = __builtin_amdgcn_mfma_f32_16x16x32_bf16(aF1[m], uF1[n], accu[m][n], 0, 0, 0);
    __builtin_amdgcn_s_setprio(0);
    BAR();
  }

#pragma unroll
  for (int m = 0; m < 8; m++) {
    const int row = m0 + wm * 128 + m * 16 + lg * 4;
#pragma unroll
    for (int n = 0; n < 2; n++) {
      const int col = n0 + wn * 32 + n * 16 + lr;
      const float bgc = bgv[col], buc = buv[col];
#pragma unroll
      for (int r = 0; r < 4; r++) {
        float gv = accg[m][n][r] + bgc;
        float uv = accu[m][n][r] + buc;
        float sg = gv / (1.0f + __expf(-gv));
        out[(size_t)(row + r) * 8192 + col] = f2bf(sg * uv);
      }
    }
  }
}

// ---------------- Flash attention (causal, GQA kv = hq%4) ----------------
__global__ __launch_bounds__(256) void attn_kernel(const u16* __restrict__ QKV,
                                                   u16* __restrict__ O) {
  const int bid = blockIdx.x;
  const int half = bid >> 8, rr = bid & 255;
  const int bh = rr >> 3, tt = rr & 7;
  const int qtile = half ? (15 - tt) : tt;
  const int b = bh >> 4, hq = bh & 15, g = hq & 3;
  const int q0 = qtile * 128;
  const int tid = threadIdx.x, l = tid & 63, w = tid >> 6;
  const int lr = l & 15, lg = l >> 4;

  __shared__ u16 kT[64 * 128] __attribute__((aligned(16)));
  __shared__ u16 vT[128 * 64] __attribute__((aligned(16)));
  __shared__ u16 pT[4][32 * 72] __attribute__((aligned(16)));

  const float scale = 0.08838834764831845f;   // 1/sqrt(128)

  bf16x8 qF[2][4];
  const int qrow_base = b * S_LEN + q0 + w * 32;
#pragma unroll
  for (int mq = 0; mq < 2; mq++)
#pragma unroll
    for (int kk = 0; kk < 4; kk++)
      qF[mq][kk] = *(const bf16x8*)(QKV + (size_t)(qrow_base + mq * 16 + lr) * DQKV
                                    + hq * 128 + kk * 32 + lg * 8);

  f32x4 o_acc[2][8] = {};
  float m_run[2][4], l_run[2][4];
#pragma unroll
  for (int mq = 0; mq < 2; mq++)
#pragma unroll
    for (int r = 0; r < 4; r++) { m_run[mq][r] = -1e30f; l_run[mq][r] = 0.0f; }

  const int qmin_w = q0 + w * 32;
  const int nt = (q0 + 128) >> 6;

  for (int it = 0; it < nt; ++it) {
    const int t0 = it * 64;
    __syncthreads();
    {
      const int rbase = tid >> 3;
      const int c16 = (tid & 7) * 16;
#pragma unroll
      for (int pass = 0; pass < 2; ++pass) {
        const int r = rbase + pass * 32;
        const u16* src = QKV + (size_t)(b * S_LEN + t0 + r) * DQKV + 2048 + g * 128 + c16;
        const int rk = r & 7;
#pragma unroll
        for (int jj = 0; jj < 2; ++jj) {
          bf16x8 kv = *(const bf16x8*)(src + jj * 8);
          const int chunk = (c16 >> 3) + jj;
          *(bf16x8*)&kT[r * 128 + ((chunk ^ rk) << 3)] = kv;
        }
#pragma unroll
        for (int jj = 0; jj < 2; ++jj) {
          bf16x8 vv = *(const bf16x8*)(src + 512 + jj * 8);
#pragma unroll
          for (int j = 0; j < 8; ++j) {
            const int d = c16 + jj * 8 + j;
            const int keyv = (d ^ (d >> 4)) & 7;
            vT[d * 64 + (r & 7) + (((r >> 3) ^ keyv) << 3)] = (u16)vv[j];
          }
        }
      }
    }
    __syncthreads();

    if (t0 <= qmin_w + 31) {
      f32x4 sc[2][4] = {};
#pragma unroll
      for (int mt = 0; mt < 4; mt++) {
        const int tq = mt * 16 + lr;
        const int tk = tq & 7;
#pragma unroll
        for (int kk = 0; kk < 4; kk++) {
          bf16x8 kF = *(const bf16x8*)&kT[tq * 128 + (((kk * 4 + lg) ^ tk) << 3)];
          sc[0][mt] = __builtin_amdgcn_mfma_f32_16x16x32_bf16(qF[0][kk], kF, sc[0][mt], 0, 0, 0);
          sc[1][mt] = __builtin_amdgcn_mfma_f32_16x16x32_bf16(qF[1][kk], kF, sc[1][mt], 0, 0, 0);
        }
      }
      const bool needMask = (t0 + 63 > qmin_w);
#pragma unroll
      for (int mq = 0; mq < 2; mq++)
#pragma unroll
        for (int mt = 0; mt < 4; mt++)
#pragma unroll
          for (int r = 0; r < 4; r++) {
            float v = sc[mq][mt][r] * scale;
            if (needMask) {
              int qg = qmin_w + mq * 16 + lg * 4 + r;
              int tg = t0 + mt * 16 + lr;
              if (tg > qg) v = -1e30f;
            }
            sc[mq][mt][r] = v;
          }
#pragma unroll
      for (int mq = 0; mq < 2; mq++) {
        float al[4];
#pragma unroll
        for (int r = 0; r < 4; r++) {
          float tmax = fmaxf(fmaxf(sc[mq][0][r], sc[mq][1][r]),
                             fmaxf(sc[mq][2][r], sc[mq][3][r]));
#pragma unroll
          for (int m = 1; m < 16; m <<= 1) tmax = fmaxf(tmax, __shfl_xor(tmax, m, 64));
          float mn = fmaxf(m_run[mq][r], tmax);
          float a = __expf(m_run[mq][r] - mn);
          m_run[mq][r] = mn;
          float rs = 0.0f;
#pragma unroll
          for (int mt = 0; mt < 4; mt++) {
            float pv = __expf(sc[mq][mt][r] - mn);
            sc[mq][mt][r] = pv;
            rs += pv;
          }
#pragma unroll
          for (int m = 1; m < 16; m <<= 1) rs += __shfl_xor(rs, m, 64);
          l_run[mq][r] = l_run[mq][r] * a + rs;
          al[r] = a;
        }
#pragma unroll
        for (int n = 0; n < 8; n++)
#pragma unroll
          for (int r = 0; r < 4; r++) o_acc[mq][n][r] *= al[r];
#pragma unroll
        for (int mt = 0; mt < 4; mt++)
#pragma unroll
          for (int r = 0; r < 4; r++)
            pT[w][(mq * 16 + lg * 4 + r) * 72 + mt * 16 + lr] = f2bf(sc[mq][mt][r]);
      }
      bf16x8 pF[2][2];
#pragma unroll
      for (int mq = 0; mq < 2; mq++)
#pragma unroll
        for (int ktp = 0; ktp < 2; ktp++)
          pF[mq][ktp] = *(const bf16x8*)&pT[w][(mq * 16 + lr) * 72 + ktp * 32 + lg * 8];
#pragma unroll
      for (int ktp = 0; ktp < 2; ktp++)
#pragma unroll
        for (int n = 0; n < 8; n++) {
          const int d = n * 16 + lr;
          const int keyv = (d ^ (d >> 4)) & 7;
          bf16x8 vF = *(const bf16x8*)&vT[d * 64 + (((ktp * 4 + lg) ^ keyv) << 3)];
          o_acc[0][n] = __builtin_amdgcn_mfma_f32_16x16x32_bf16(pF[0][ktp], vF, o_acc[0][n], 0, 0, 0);
          o_acc[1][n] = __builtin_amdgcn_mfma_f32_16x16x32_bf16(pF[1][ktp], vF, o_acc[1][n], 0, 0, 0);
        }
    }
  }
#pragma unroll
  for (int mq = 0; mq < 2; mq++)
#pragma unroll
    for (int n = 0; n < 8; n++)
#pragma unroll
      for (int r = 0; r < 4; r++) {
        float v = o_acc[mq][n][r] / l_run[mq][r];
        int row = b * S_LEN + q0 + w * 32 + mq * 16 + lg * 4 + r;
        int col = hq * 128 + n * 16 + lr;
        O[(size_t)row * 2048 + col] = f2bf(v);
      }
}

// ---------------- launch ----------------
extern "C" void kernel_launch(void* const* d_in, const int* in_sizes, int n_in,
                              void* d_out, int out_size, void* d_ws, size_t ws_size,
                              hipStream_t stream) {
  const float* x  = (const float*)d_in[0];
  const float* Wq = (const float*)d_in[2];
  const float* Wk = (const float*)d_in[3];
  const float* Wv = (const float*)d_in[4];
  const float* Wo = (const float*)d_in[5];
  const float* Wg = (const float*)d_in[6];
  const float* bg = (const float*)d_in[7];
  const float* Wu = (const float*)d_in[8];
  const float* bu = (const float*)d_in[9];
  const float* Wd = (const float*)d_in[10];
  const float* bd = (const float*)d_in[11];
  const float* g1 = (const float*)d_in[12];
  const float* g2 = (const float*)d_in[13];

  char* p = (char*)d_ws;
  auto alloc = [&](size_t bytes) { char* r = p; p += (bytes + 255) & ~(size_t)255; return r; };
  u16*   BtQKV = (u16*)alloc((size_t)DQKV * 2048 * 2);
  u16*   WoT   = (u16*)alloc((size_t)2048 * 2048 * 2);
  u16*   WgT   = (u16*)alloc((size_t)8192 * 2048 * 2);
  u16*   WuT   = (u16*)alloc((size_t)8192 * 2048 * 2);
  u16*   WdT   = (u16*)alloc((size_t)2048 * 8192 * 2);
  u16*   xn    = (u16*)alloc((size_t)NROW * 2048 * 2);   // also hn
  u16*   QKV   = (u16*)alloc((size_t)NROW * DQKV * 2);
  u16*   Obuf  = (u16*)alloc((size_t)NROW * 2048 * 2);
  float* h     = (float*)alloc((size_t)NROW * 2048 * 4);
  u16*   gact  = (u16*)alloc((size_t)NROW * 8192 * 2);
  float* cosT  = (float*)alloc((size_t)S_LEN * 64 * 4);
  float* sinT  = (float*)alloc((size_t)S_LEN * 64 * 4);

  dim3 tb(32, 8);
  transpose_f32_bf16<<<dim3(2048/32, 2048/32), tb, 0, stream>>>(Wq, BtQKV,                2048, 2048);
  transpose_f32_bf16<<<dim3( 512/32, 2048/32), tb, 0, stream>>>(Wk, BtQKV + 2048ull*2048, 2048,  512);
  transpose_f32_bf16<<<dim3( 512/32, 2048/32), tb, 0, stream>>>(Wv, BtQKV + 2560ull*2048, 2048,  512);
  transpose_f32_bf16<<<dim3(2048/32, 2048/32), tb, 0, stream>>>(Wo, WoT,                  2048, 2048);
  transpose_f32_bf16<<<dim3(8192/32, 2048/32), tb, 0, stream>>>(Wg, WgT,                  2048, 8192);
  transpose_f32_bf16<<<dim3(8192/32, 2048/32), tb, 0, stream>>>(Wu, WuT,                  2048, 8192);
  transpose_f32_bf16<<<dim3(2048/32, 8192/32), tb, 0, stream>>>(Wd, WdT,                  8192, 2048);

  rope_tables<<<(S_LEN * 64) / 256, 256, 0, stream>>>(cosT, sinT);

  rmsnorm_kernel<<<NROW, 256, 0, stream>>>(x, g1, xn);

  gemm8p<256, 0><<<192, 512, 0, stream>>>(xn, BtQKV, 12, 2048, 3072,
                                          nullptr, nullptr, QKV, nullptr);

  rope_apply<<<(NROW * 20 * 64) / 256, 256, 0, stream>>>(QKV, cosT, sinT);

  attn_kernel<<<512, 256, 0, stream>>>(QKV, Obuf);

  gemm8p<128, 1><<<256, 512, 0, stream>>>(Obuf, WoT, 16, 2048, 2048,
                                          nullptr, x, nullptr, h);

  rmsnorm_kernel<<<NROW, 256, 0, stream>>>(h, g2, xn);

  swiglu8p<<<1024, 512, 0, stream>>>(xn, WgT, WuT, 64, 2048, bg, bu, gact);

  gemm8p<128, 1><<<256, 512, 0, stream>>>(gact, WdT, 16, 8192, 2048,
                                          bd, h, nullptr, (float*)d_out);
}

// Round 5
// 802.856 us; speedup vs baseline: 1.0329x; 1.0329x over previous
//
#include <hip/hip_runtime.h>
#include <hip/hip_bf16.h>
#include <stdint.h>

#define S_LEN 2048
#define NROW  4096            // B*S
#define DQKV  3072            // 2048 Q + 512 K + 512 V

typedef unsigned short u16;
typedef __attribute__((ext_vector_type(8))) short bf16x8;
typedef __attribute__((ext_vector_type(4))) float f32x4;

__device__ __forceinline__ float bf2f(u16 v) {
  unsigned int u = ((unsigned int)v) << 16;
  return __builtin_bit_cast(float, u);
}
__device__ __forceinline__ u16 f2bf(float f) {
  unsigned int u = __builtin_bit_cast(unsigned int, f);
  u += 0x7FFFu + ((u >> 16) & 1u);
  return (u16)(u >> 16);
}
__device__ __forceinline__ void async16(const void* g, void* l) {
  __builtin_amdgcn_global_load_lds(
      (const __attribute__((address_space(1))) unsigned int*)(uintptr_t)g,
      (__attribute__((address_space(3))) unsigned int*)(uintptr_t)l, 16, 0, 0);
}
#define SB()    __builtin_amdgcn_sched_barrier(0)
#define LGKM0   do { asm volatile("s_waitcnt lgkmcnt(0)" ::: "memory"); SB(); } while (0)
#define LGKM8   do { asm volatile("s_waitcnt lgkmcnt(8)" ::: "memory"); } while (0)
#define VMC4    do { asm volatile("s_waitcnt vmcnt(4)" ::: "memory"); SB(); } while (0)
#define BAR()   __builtin_amdgcn_s_barrier()

// ---------------- transpose f32 [R][C] -> bf16 [C][R] ----------------
__global__ __launch_bounds__(256) void transpose_f32_bf16(
    const float* __restrict__ in, u16* __restrict__ out, int R, int C) {
  __shared__ float t[32][33];
  const int bx = blockIdx.x * 32;
  const int by = blockIdx.y * 32;
  const int tx = threadIdx.x, ty = threadIdx.y;   // 32 x 8
#pragma unroll
  for (int i = 0; i < 32; i += 8)
    t[ty + i][tx] = in[(size_t)(by + ty + i) * C + bx + tx];
  __syncthreads();
#pragma unroll
  for (int i = 0; i < 32; i += 8)
    out[(size_t)(bx + ty + i) * R + by + tx] = f2bf(t[tx][ty + i]);
}

// ---------------- RoPE tables ----------------
__global__ __launch_bounds__(256) void rope_tables(float* __restrict__ cosT,
                                                   float* __restrict__ sinT) {
  int idx = blockIdx.x * 256 + threadIdx.x;   // 2048*64
  int i = idx & 63, s = idx >> 6;
  float inv = powf(10000.0f, -2.0f * (float)i / 128.0f);
  float ang = (float)s * inv;
  cosT[idx] = cosf(ang);
  sinT[idx] = sinf(ang);
}

// ---------------- RoPE in-place on QKV ----------------
__global__ __launch_bounds__(256) void rope_apply(u16* __restrict__ QKV,
                                                  const float* __restrict__ cosT,
                                                  const float* __restrict__ sinT) {
  int idx = blockIdx.x * 256 + threadIdx.x;        // NROW*20*64
  int i = idx & 63;
  int h20 = (idx >> 6) % 20;
  int row = idx / (64 * 20);
  int s = row & (S_LEN - 1);
  int col = (h20 < 16) ? (h20 * 128) : (2048 + (h20 - 16) * 128);
  size_t base = (size_t)row * DQKV + col;
  float v1 = bf2f(QKV[base + i]);
  float v2 = bf2f(QKV[base + 64 + i]);
  float c = cosT[s * 64 + i], sn = sinT[s * 64 + i];
  QKV[base + i]      = f2bf(v1 * c - v2 * sn);
  QKV[base + 64 + i] = f2bf(v1 * sn + v2 * c);
}

// ---------------- RMSNorm: f32 [rows][2048] -> bf16 ----------------
__global__ __launch_bounds__(256) void rmsnorm_kernel(const float* __restrict__ x,
                                                      const float* __restrict__ g,
                                                      u16* __restrict__ out) {
  const int row = blockIdx.x, tid = threadIdx.x;
  const float* xr = x + (size_t)row * 2048;
  float4 a = ((const float4*)xr)[tid * 2];
  float4 b = ((const float4*)xr)[tid * 2 + 1];
  float ss = a.x*a.x + a.y*a.y + a.z*a.z + a.w*a.w
           + b.x*b.x + b.y*b.y + b.z*b.z + b.w*b.w;
#pragma unroll
  for (int m = 1; m < 64; m <<= 1) ss += __shfl_xor(ss, m, 64);
  __shared__ float red[4];
  if ((tid & 63) == 0) red[tid >> 6] = ss;
  __syncthreads();
  float tot = red[0] + red[1] + red[2] + red[3];
  float rms = rsqrtf(tot * (1.0f / 2048.0f) + 1e-5f);
  const int c = tid * 8;
  float v[8] = {a.x,a.y,a.z,a.w,b.x,b.y,b.z,b.w};
  u16 o[8];
#pragma unroll
  for (int j = 0; j < 8; j++) o[j] = f2bf(v[j] * rms * g[c + j]);
  *(uint4*)(out + (size_t)row * 2048 + c) = *(uint4*)o;
}

// ======================= 4-phase double-buffered GEMM =======================
// m201-faithful phase: {ds_read; stage; [lgkm8]; BAR; lgkm0; prio1 MFMA prio0; BAR}
// BM=256, BK=64, 8 waves (2m x 4n), 512 thr. Chunk swizzle slot = chunk^(row&7).
// Stages: B0(t+1)@p0, B1(t+1)@p1, A0(t+2)@p2, A1(t+2)@p3. vmcnt(4) once @p3.
template <int BN, int MODE>
__global__ __launch_bounds__(512, 2) void gemm8p(
    const u16* __restrict__ A, const u16* __restrict__ Bt,
    int nx, int K, int N,
    const float* __restrict__ bias, const float* __restrict__ res,
    u16* __restrict__ outb, float* __restrict__ outf) {
  constexpr int NF = BN / 64;            // frags per wave in n (4 or 2)
  constexpr int BB = BN * 128;           // bytes per B buffer
  __shared__ char ldsA[2 * 32768] __attribute__((aligned(16)));
  __shared__ char ldsB[2 * BB]    __attribute__((aligned(16)));
  const int t = threadIdx.x;
  const int nwg = gridDim.x;
  const int wg = ((int)blockIdx.x & 7) * (nwg >> 3) + ((int)blockIdx.x >> 3);
  const int m0 = (wg / nx) * 256, n0 = (wg % nx) * BN;
  const int l = t & 63, w = t >> 6;
  const int wm = w >> 2, wn = w & 3;
  const int lr = l & 15, lg = l >> 4;

  const size_t K2 = (size_t)K * 2;
  const int pr = t >> 3;                          // 0..63
  const int ckb = ((t & 7) ^ (pr & 7)) * 16;      // swizzled source chunk
  const int t16 = t * 16;
  const char* aSrc = (const char*)A  + (size_t)(m0 + pr) * K2 + ckb;
  const char* bSrc = (const char*)Bt + (size_t)(n0 + pr) * K2 + ckb;

  auto ST_A = [&](int q, int kt, int buf) {
    char* d = ldsA + buf * 32768 + q * 16384 + t16;
    const char* s = aSrc + (size_t)(q * 128) * K2 + (size_t)kt * 128;
    async16(s, d);
    async16(s + (size_t)64 * K2, d + 8192);
  };
  auto ST_B = [&](int h, int kt, int buf) {
    if constexpr (BN == 256) {
      char* d = ldsB + buf * 32768 + h * 16384 + t16;
      const char* s = bSrc + (size_t)(h * 128) * K2 + (size_t)kt * 128;
      async16(s, d);
      async16(s + (size_t)64 * K2, d + 8192);
    } else {
      char* d = ldsB + buf * 16384 + h * 8192 + t16;
      const char* s = bSrc + (size_t)(h * 64) * K2 + (size_t)kt * 128;
      async16(s, d);
    }
  };

  const int NT = K >> 6;
  // prologue: tile0 (A,B) -> buf0; tile1 A -> buf1 (B(1) staged during tile 0)
  ST_A(0, 0, 0); ST_A(1, 0, 0); ST_B(0, 0, 0); ST_B(1, 0, 0);
  ST_A(0, 1, 1); ST_A(1, 1, 1);
  VMC4;           // tile0's A+B landed (A(1)'s 4 loads may remain in flight)
  BAR();

  // read addressing
  const int key = lr & 7;
  const int c0 = (lg ^ key) * 16;
  const int c1 = ((4 + lg) ^ key) * 16;
  const int aB = wm * 16384 + lr * 128;
  const int bB = (BN == 256) ? ((wn >> 1) * 16384 + ((wn & 1) * 64 + lr) * 128)
                             : ((wn >> 1) * 8192  + ((wn & 1) * 32 + lr) * 128);

  f32x4 acc[8][NF] = {};

  for (int kt = 0; kt < NT; ++kt) {
    const int bufc = kt & 1, bufn = bufc ^ 1;
    const int t1 = (kt + 1 < NT) ? kt + 1 : 0;
    const int t2 = (kt + 2 < NT) ? kt + 2 : kt + 2 - NT;
    const char* sA = ldsA + bufc * 32768;
    const char* sB = ldsB + bufc * BB;
    bf16x8 aF0[8], aF1[8], bF0[NF], bF1[NF];
    // ---- phase 0: read A-kh0 + B-kh0 (12/10); stage B0(t+1); mfma kh0 m0-3
#pragma unroll
    for (int m = 0; m < 8; m++) aF0[m] = *(const bf16x8*)(sA + aB + m * 2048 + c0);
#pragma unroll
    for (int n = 0; n < NF; n++) bF0[n] = *(const bf16x8*)(sB + bB + n * 2048 + c0);
    ST_B(0, t1, bufn);
    LGKM8;
    SB(); BAR();
    LGKM0;
    __builtin_amdgcn_s_setprio(1);
#pragma unroll
    for (int m = 0; m < 4; m++)
#pragma unroll
      for (int n = 0; n < NF; n++)
        acc[m][n] = __builtin_amdgcn_mfma_f32_16x16x32_bf16(aF0[m], bF0[n], acc[m][n], 0, 0, 0);
    __builtin_amdgcn_s_setprio(0);
    SB(); BAR();
    // ---- phase 1: read A-kh1 (8); stage B1(t+1); mfma kh0 m4-7
#pragma unroll
    for (int m = 0; m < 8; m++) aF1[m] = *(const bf16x8*)(sA + aB + m * 2048 + c1);
    ST_B(1, t1, bufn);
    SB(); BAR();
    LGKM0;   // ALL A reads done before p1-exit barrier -> A recycle at p2 is safe
    __builtin_amdgcn_s_setprio(1);
#pragma unroll
    for (int m = 4; m < 8; m++)
#pragma unroll
      for (int n = 0; n < NF; n++)
        acc[m][n] = __builtin_amdgcn_mfma_f32_16x16x32_bf16(aF0[m], bF0[n], acc[m][n], 0, 0, 0);
    __builtin_amdgcn_s_setprio(0);
    SB(); BAR();
    // ---- phase 2: read B-kh1 (NF); stage A0(t+2) into current buf; mfma kh1 m0-3
#pragma unroll
    for (int n = 0; n < NF; n++) bF1[n] = *(const bf16x8*)(sB + bB + n * 2048 + c1);
    ST_A(0, t2, bufc);
    SB(); BAR();
    LGKM0;
    __builtin_amdgcn_s_setprio(1);
#pragma unroll
    for (int m = 0; m < 4; m++)
#pragma unroll
      for (int n = 0; n < NF; n++)
        acc[m][n] = __builtin_amdgcn_mfma_f32_16x16x32_bf16(aF1[m], bF1[n], acc[m][n], 0, 0, 0);
    __builtin_amdgcn_s_setprio(0);
    SB(); BAR();
    // ---- phase 3: no reads; stage A1(t+2); vmcnt(4); mfma kh1 m4-7
    ST_A(1, t2, bufc);
    VMC4;    // certifies B(t+1) landed (A(t+2) may stay in flight)
    SB(); BAR();
    __builtin_amdgcn_s_setprio(1);
#pragma unroll
    for (int m = 4; m < 8; m++)
#pragma unroll
      for (int n = 0; n < NF; n++)
        acc[m][n] = __builtin_amdgcn_mfma_f32_16x16x32_bf16(aF1[m], bF1[n], acc[m][n], 0, 0, 0);
    __builtin_amdgcn_s_setprio(0);
    SB(); BAR();
  }

#pragma unroll
  for (int m = 0; m < 8; m++) {
    const int row = m0 + wm * 128 + m * 16 + lg * 4;
#pragma unroll
    for (int n = 0; n < NF; n++) {
      const int col = n0 + wn * (BN / 4) + n * 16 + lr;
      const float bv = bias ? bias[col] : 0.0f;
#pragma unroll
      for (int r = 0; r < 4; r++) {
        const size_t idx = (size_t)(row + r) * N + col;
        float v = acc[m][n][r] + bv;
        if (MODE == 0) outb[idx] = f2bf(v);
        else           outf[idx] = v + res[idx];
      }
    }
  }
}

// ============ fused SwiGLU, same m201-faithful 4-phase schedule ============
__global__ __launch_bounds__(512, 2) void swiglu8p(
    const u16* __restrict__ A, const u16* __restrict__ Bg, const u16* __restrict__ Bu,
    int nx, int K, const float* __restrict__ bgv, const float* __restrict__ buv,
    u16* __restrict__ out) {
  __shared__ char ldsA[2 * 32768] __attribute__((aligned(16)));
  __shared__ char ldsB[2 * 32768] __attribute__((aligned(16)));
  const int t = threadIdx.x;
  const int nwg = gridDim.x;
  const int wg = ((int)blockIdx.x & 7) * (nwg >> 3) + ((int)blockIdx.x >> 3);
  const int m0 = (wg / nx) * 256, n0 = (wg % nx) * 128;
  const int l = t & 63, w = t >> 6;
  const int wm = w >> 2, wn = w & 3;
  const int lr = l & 15, lg = l >> 4;

  const size_t K2 = (size_t)K * 2;
  const int pr = t >> 3;
  const int ckb = ((t & 7) ^ (pr & 7)) * 16;
  const int t16 = t * 16;
  const char* aSrc = (const char*)A  + (size_t)(m0 + pr) * K2 + ckb;
  const char* gSrc = (const char*)Bg + (size_t)(n0 + pr) * K2 + ckb;
  const char* uSrc = (const char*)Bu + (size_t)(n0 + pr) * K2 + ckb;

  auto ST_A = [&](int q, int kt, int buf) {
    char* d = ldsA + buf * 32768 + q * 16384 + t16;
    const char* s = aSrc + (size_t)(q * 128) * K2 + (size_t)kt * 128;
    async16(s, d);
    async16(s + (size_t)64 * K2, d + 8192);
  };
  auto ST_GU = [&](int h, int kt, int buf) {   // h=0: g, h=1: u
    char* d = ldsB + buf * 32768 + h * 16384 + t16;
    const char* s = (h ? uSrc : gSrc) + (size_t)kt * 128;
    async16(s, d);
    async16(s + (size_t)64 * K2, d + 8192);
  };

  const int NT = K >> 6;
  ST_A(0, 0, 0); ST_A(1, 0, 0); ST_GU(0, 0, 0); ST_GU(1, 0, 0);
  ST_A(0, 1, 1); ST_A(1, 1, 1);
  VMC4;
  BAR();

  const int key = lr & 7;
  const int c0 = (lg ^ key) * 16;
  const int c1 = ((4 + lg) ^ key) * 16;
  const int aB = wm * 16384 + lr * 128;
  const int gB = (wn * 32 + lr) * 128;

  f32x4 accg[8][2] = {}, accu[8][2] = {};

  for (int kt = 0; kt < NT; ++kt) {
    const int bufc = kt & 1, bufn = bufc ^ 1;
    const int t1 = (kt + 1 < NT) ? kt + 1 : 0;
    const int t2 = (kt + 2 < NT) ? kt + 2 : kt + 2 - NT;
    const char* sA = ldsA + bufc * 32768;
    const char* sB = ldsB + bufc * 32768;
    bf16x8 aF0[8], aF1[8], gF0[2], gF1[2], uF0[2], uF1[2];
    // ---- phase 0: read A-kh0 + g/u-kh0 (12); stage G(t+1); mfma g-kh0
#pragma unroll
    for (int m = 0; m < 8; m++) aF0[m] = *(const bf16x8*)(sA + aB + m * 2048 + c0);
#pragma unroll
    for (int n = 0; n < 2; n++) {
      gF0[n] = *(const bf16x8*)(sB + gB + n * 2048 + c0);
      uF0[n] = *(const bf16x8*)(sB + 16384 + gB + n * 2048 + c0);
    }
    ST_GU(0, t1, bufn);
    LGKM8;
    SB(); BAR();
    LGKM0;
    __builtin_amdgcn_s_setprio(1);
#pragma unroll
    for (int m = 0; m < 8; m++)
#pragma unroll
      for (int n = 0; n < 2; n++)
        accg[m][n] = __builtin_amdgcn_mfma_f32_16x16x32_bf16(aF0[m], gF0[n], accg[m][n], 0, 0, 0);
    __builtin_amdgcn_s_setprio(0);
    SB(); BAR();
    // ---- phase 1: read A-kh1 (8); stage U(t+1); mfma u-kh0
#pragma unroll
    for (int m = 0; m < 8; m++) aF1[m] = *(const bf16x8*)(sA + aB + m * 2048 + c1);
    ST_GU(1, t1, bufn);
    SB(); BAR();
    LGKM0;   // all A reads done before p1-exit barrier
    __builtin_amdgcn_s_setprio(1);
#pragma unroll
    for (int m = 0; m < 8; m++)
#pragma unroll
      for (int n = 0; n < 2; n++)
        accu[m][n] = __builtin_amdgcn_mfma_f32_16x16x32_bf16(aF0[m], uF0[n], accu[m][n], 0, 0, 0);
    __builtin_amdgcn_s_setprio(0);
    SB(); BAR();
    // ---- phase 2: read g/u-kh1 (4); stage A0(t+2); mfma g-kh1
#pragma unroll
    for (int n = 0; n < 2; n++) {
      gF1[n] = *(const bf16x8*)(sB + gB + n * 2048 + c1);
      uF1[n] = *(const bf16x8*)(sB + 16384 + gB + n * 2048 + c1);
    }
    ST_A(0, t2, bufc);
    SB(); BAR();
    LGKM0;
    __builtin_amdgcn_s_setprio(1);
#pragma unroll
    for (int m = 0; m < 8; m++)
#pragma unroll
      for (int n = 0; n < 2; n++)
        accg[m][n] = __builtin_amdgcn_mfma_f32_16x16x32_bf16(aF1[m], gF1[n], accg[m][n], 0, 0, 0);
    __builtin_amdgcn_s_setprio(0);
    SB(); BAR();
    // ---- phase 3: no reads; stage A1(t+2); vmcnt(4); mfma u-kh1
    ST_A(1, t2, bufc);
    VMC4;
    SB(); BAR();
    __builtin_amdgcn_s_setprio(1);
#pragma unroll
    for (int m = 0; m < 8; m++)
#pragma unroll
      for (int n = 0; n < 2; n++)
        accu[m][n] = __builtin_amdgcn_mfma_f32_16x16x32_bf16(aF1[m], uF1[n], accu[m][n], 0, 0, 0);
    __builtin_amdgcn_s_setprio(0);
    SB(); BAR();
  }

#pragma unroll
  for (int m = 0; m < 8; m++) {
    const int row = m0 + wm * 128 + m * 16 + lg * 4;
#pragma unroll
    for (int n = 0; n < 2; n++) {
      const int col = n0 + wn * 32 + n * 16 + lr;
      const float bgc = bgv[col], buc = buv[col];
#pragma unroll
      for (int r = 0; r < 4; r++) {
        float gv = accg[m][n][r] + bgc;
        float uv = accu[m][n][r] + buc;
        float sg = gv / (1.0f + __expf(-gv));
        out[(size_t)(row + r) * 8192 + col] = f2bf(sg * uv);
      }
    }
  }
}

// ---------------- Flash attention (causal, GQA kv = hq%4) ----------------
__global__ __launch_bounds__(256) void attn_kernel(const u16* __restrict__ QKV,
                                                   u16* __restrict__ O) {
  const int bid = blockIdx.x;
  const int half = bid >> 8, rr = bid & 255;
  const int bh = rr >> 3, tt = rr & 7;
  const int qtile = half ? (15 - tt) : tt;
  const int b = bh >> 4, hq = bh & 15, g = hq & 3;
  const int q0 = qtile * 128;
  const int tid = threadIdx.x, l = tid & 63, w = tid >> 6;
  const int lr = l & 15, lg = l >> 4;

  __shared__ u16 kT[64 * 128] __attribute__((aligned(16)));
  __shared__ u16 vT[128 * 64] __attribute__((aligned(16)));
  __shared__ u16 pT[4][32 * 72] __attribute__((aligned(16)));

  const float scale = 0.08838834764831845f;   // 1/sqrt(128)

  bf16x8 qF[2][4];
  const int qrow_base = b * S_LEN + q0 + w * 32;
#pragma unroll
  for (int mq = 0; mq < 2; mq++)
#pragma unroll
    for (int kk = 0; kk < 4; kk++)
      qF[mq][kk] = *(const bf16x8*)(QKV + (size_t)(qrow_base + mq * 16 + lr) * DQKV
                                    + hq * 128 + kk * 32 + lg * 8);

  f32x4 o_acc[2][8] = {};
  float m_run[2][4], l_run[2][4];
#pragma unroll
  for (int mq = 0; mq < 2; mq++)
#pragma unroll
    for (int r = 0; r < 4; r++) { m_run[mq][r] = -1e30f; l_run[mq][r] = 0.0f; }

  const int qmin_w = q0 + w * 32;
  const int nt = (q0 + 128) >> 6;

  for (int it = 0; it < nt; ++it) {
    const int t0 = it * 64;
    __syncthreads();
    {
      const int rbase = tid >> 3;
      const int c16 = (tid & 7) * 16;
#pragma unroll
      for (int pass = 0; pass < 2; ++pass) {
        const int r = rbase + pass * 32;
        const u16* src = QKV + (size_t)(b * S_LEN + t0 + r) * DQKV + 2048 + g * 128 + c16;
        const int rk = r & 7;
#pragma unroll
        for (int jj = 0; jj < 2; ++jj) {
          bf16x8 kv = *(const bf16x8*)(src + jj * 8);
          const int chunk = (c16 >> 3) + jj;
          *(bf16x8*)&kT[r * 128 + ((chunk ^ rk) << 3)] = kv;
        }
#pragma unroll
        for (int jj = 0; jj < 2; ++jj) {
          bf16x8 vv = *(const bf16x8*)(src + 512 + jj * 8);
#pragma unroll
          for (int j = 0; j < 8; ++j) {
            const int d = c16 + jj * 8 + j;
            const int keyv = (d ^ (d >> 4)) & 7;
            vT[d * 64 + (r & 7) + (((r >> 3) ^ keyv) << 3)] = (u16)vv[j];
          }
        }
      }
    }
    __syncthreads();

    if (t0 <= qmin_w + 31) {
      f32x4 sc[2][4] = {};
#pragma unroll
      for (int mt = 0; mt < 4; mt++) {
        const int tq = mt * 16 + lr;
        const int tk = tq & 7;
#pragma unroll
        for (int kk = 0; kk < 4; kk++) {
          bf16x8 kF = *(const bf16x8*)&kT[tq * 128 + (((kk * 4 + lg) ^ tk) << 3)];
          sc[0][mt] = __builtin_amdgcn_mfma_f32_16x16x32_bf16(qF[0][kk], kF, sc[0][mt], 0, 0, 0);
          sc[1][mt] = __builtin_amdgcn_mfma_f32_16x16x32_bf16(qF[1][kk], kF, sc[1][mt], 0, 0, 0);
        }
      }
      const bool needMask = (t0 + 63 > qmin_w);
#pragma unroll
      for (int mq = 0; mq < 2; mq++)
#pragma unroll
        for (int mt = 0; mt < 4; mt++)
#pragma unroll
          for (int r = 0; r < 4; r++) {
            float v = sc[mq][mt][r] * scale;
            if (needMask) {
              int qg = qmin_w + mq * 16 + lg * 4 + r;
              int tg = t0 + mt * 16 + lr;
              if (tg > qg) v = -1e30f;
            }
            sc[mq][mt][r] = v;
          }
#pragma unroll
      for (int mq = 0; mq < 2; mq++) {
        float al[4];
#pragma unroll
        for (int r = 0; r < 4; r++) {
          float tmax = fmaxf(fmaxf(sc[mq][0][r], sc[mq][1][r]),
                             fmaxf(sc[mq][2][r], sc[mq][3][r]));
#pragma unroll
          for (int m = 1; m < 16; m <<= 1) tmax = fmaxf(tmax, __shfl_xor(tmax, m, 64));
          float mn = fmaxf(m_run[mq][r], tmax);
          float a = __expf(m_run[mq][r] - mn);
          m_run[mq][r] = mn;
          float rs = 0.0f;
#pragma unroll
          for (int mt = 0; mt < 4; mt++) {
            float pv = __expf(sc[mq][mt][r] - mn);
            sc[mq][mt][r] = pv;
            rs += pv;
          }
#pragma unroll
          for (int m = 1; m < 16; m <<= 1) rs += __shfl_xor(rs, m, 64);
          l_run[mq][r] = l_run[mq][r] * a + rs;
          al[r] = a;
        }
#pragma unroll
        for (int n = 0; n < 8; n++)
#pragma unroll
          for (int r = 0; r < 4; r++) o_acc[mq][n][r] *= al[r];
#pragma unroll
        for (int mt = 0; mt < 4; mt++)
#pragma unroll
          for (int r = 0; r < 4; r++)
            pT[w][(mq * 16 + lg * 4 + r) * 72 + mt * 16 + lr] = f2bf(sc[mq][mt][r]);
      }
      bf16x8 pF[2][2];
#pragma unroll
      for (int mq = 0; mq < 2; mq++)
#pragma unroll
        for (int ktp = 0; ktp < 2; ktp++)
          pF[mq][ktp] = *(const bf16x8*)&pT[w][(mq * 16 + lr) * 72 + ktp * 32 + lg * 8];
#pragma unroll
      for (int ktp = 0; ktp < 2; ktp++)
#pragma unroll
        for (int n = 0; n < 8; n++) {
          const int d = n * 16 + lr;
          const int keyv = (d ^ (d >> 4)) & 7;
          bf16x8 vF = *(const bf16x8*)&vT[d * 64 + (((ktp * 4 + lg) ^ keyv) << 3)];
          o_acc[0][n] = __builtin_amdgcn_mfma_f32_16x16x32_bf16(pF[0][ktp], vF, o_acc[0][n], 0, 0, 0);
          o_acc[1][n] = __builtin_amdgcn_mfma_f32_16x16x32_bf16(pF[1][ktp], vF, o_acc[1][n], 0, 0, 0);
        }
    }
  }
#pragma unroll
  for (int mq = 0; mq < 2; mq++)
#pragma unroll
    for (int n = 0; n < 8; n++)
#pragma unroll
      for (int r = 0; r < 4; r++) {
        float v = o_acc[mq][n][r] / l_run[mq][r];
        int row = b * S_LEN + q0 + w * 32 + mq * 16 + lg * 4 + r;
        int col = hq * 128 + n * 16 + lr;
        O[(size_t)row * 2048 + col] = f2bf(v);
      }
}

// ---------------- launch ----------------
extern "C" void kernel_launch(void* const* d_in, const int* in_sizes, int n_in,
                              void* d_out, int out_size, void* d_ws, size_t ws_size,
                              hipStream_t stream) {
  const float* x  = (const float*)d_in[0];
  const float* Wq = (const float*)d_in[2];
  const float* Wk = (const float*)d_in[3];
  const float* Wv = (const float*)d_in[4];
  const float* Wo = (const float*)d_in[5];
  const float* Wg = (const float*)d_in[6];
  const float* bg = (const float*)d_in[7];
  const float* Wu = (const float*)d_in[8];
  const float* bu = (const float*)d_in[9];
  const float* Wd = (const float*)d_in[10];
  const float* bd = (const float*)d_in[11];
  const float* g1 = (const float*)d_in[12];
  const float* g2 = (const float*)d_in[13];

  char* p = (char*)d_ws;
  auto alloc = [&](size_t bytes) { char* r = p; p += (bytes + 255) & ~(size_t)255; return r; };
  u16*   BtQKV = (u16*)alloc((size_t)DQKV * 2048 * 2);
  u16*   WoT   = (u16*)alloc((size_t)2048 * 2048 * 2);
  u16*   WgT   = (u16*)alloc((size_t)8192 * 2048 * 2);
  u16*   WuT   = (u16*)alloc((size_t)8192 * 2048 * 2);
  u16*   WdT   = (u16*)alloc((size_t)2048 * 8192 * 2);
  u16*   xn    = (u16*)alloc((size_t)NROW * 2048 * 2);   // also hn
  u16*   QKV   = (u16*)alloc((size_t)NROW * DQKV * 2);
  u16*   Obuf  = (u16*)alloc((size_t)NROW * 2048 * 2);
  float* h     = (float*)alloc((size_t)NROW * 2048 * 4);
  u16*   gact  = (u16*)alloc((size_t)NROW * 8192 * 2);
  float* cosT  = (float*)alloc((size_t)S_LEN * 64 * 4);
  float* sinT  = (float*)alloc((size_t)S_LEN * 64 * 4);

  dim3 tb(32, 8);
  transpose_f32_bf16<<<dim3(2048/32, 2048/32), tb, 0, stream>>>(Wq, BtQKV,                2048, 2048);
  transpose_f32_bf16<<<dim3( 512/32, 2048/32), tb, 0, stream>>>(Wk, BtQKV + 2048ull*2048, 2048,  512);
  transpose_f32_bf16<<<dim3( 512/32, 2048/32), tb, 0, stream>>>(Wv, BtQKV + 2560ull*2048, 2048,  512);
  transpose_f32_bf16<<<dim3(2048/32, 2048/32), tb, 0, stream>>>(Wo, WoT,                  2048, 2048);
  transpose_f32_bf16<<<dim3(8192/32, 2048/32), tb, 0, stream>>>(Wg, WgT,                  2048, 8192);
  transpose_f32_bf16<<<dim3(8192/32, 2048/32), tb, 0, stream>>>(Wu, WuT,                  2048, 8192);
  transpose_f32_bf16<<<dim3(2048/32, 8192/32), tb, 0, stream>>>(Wd, WdT,                  8192, 2048);

  rope_tables<<<(S_LEN * 64) / 256, 256, 0, stream>>>(cosT, sinT);

  rmsnorm_kernel<<<NROW, 256, 0, stream>>>(x, g1, xn);

  gemm8p<256, 0><<<192, 512, 0, stream>>>(xn, BtQKV, 12, 2048, 3072,
                                          nullptr, nullptr, QKV, nullptr);

  rope_apply<<<(NROW * 20 * 64) / 256, 256, 0, stream>>>(QKV, cosT, sinT);

  attn_kernel<<<512, 256, 0, stream>>>(QKV, Obuf);

  gemm8p<128, 1><<<256, 512, 0, stream>>>(Obuf, WoT, 16, 2048, 2048,
                                          nullptr, x, nullptr, h);

  rmsnorm_kernel<<<NROW, 256, 0, stream>>>(h, g2, xn);

  swiglu8p<<<1024, 512, 0, stream>>>(xn, WgT, WuT, 64, 2048, bg, bu, gact);

  gemm8p<128, 1><<<256, 512, 0, stream>>>(gact, WdT, 16, 8192, 2048,
                                          bd, h, nullptr, (float*)d_out);
}